// Round 1
// baseline (225.854 us; speedup 1.0000x reference)
//
#include <hip/hip_runtime.h>
#include <hip/hip_bf16.h>

#define BATCH        16384
#define SEQ          500
#define NUM_BUCKETS  4000000
#define NUM_FIELDS   63
#define NUM_SEGMENTS 64
#define BLOCK        256
#define NWAVES       (BLOCK / 64)

__global__ __launch_bounds__(BLOCK) void wide_pool_kernel(
    const int*   __restrict__ indexes,   // [BATCH*SEQ] raw ids (i32, < 1e8)
    const int*   __restrict__ fields,    // [BATCH*SEQ] segment ids in [0,64)
    const float* __restrict__ values,    // [BATCH*SEQ]
    const float* __restrict__ table,     // [NUM_BUCKETS] (dim-1 embedding)
    float*       __restrict__ out)       // [BATCH, NUM_FIELDS]
{
    // Per-wave private accumulators: 4 waves x 64 segments. 64 lanes scatter
    // onto 64 slots -> low LDS-atomic contention; cross-wave combine at end.
    __shared__ float acc[NWAVES][NUM_SEGMENTS];

    const int b    = blockIdx.x;
    const int tid  = threadIdx.x;
    const int wave = tid >> 6;

    // zero accumulators (256 threads, 256 slots)
    acc[tid >> 6][tid & 63] = 0.0f;
    __syncthreads();

    const long base = (long)b * SEQ;
    for (int s = tid; s < SEQ; s += BLOCK) {
        const int   idx = indexes[base + s];
        const int   f   = fields[base + s];
        const float v   = values[base + s];
        const int   bucket = idx % NUM_BUCKETS;          // magic-mul, no div unit
        // padding_idx = 0: row 0 contributes nothing
        const float e = (bucket == 0) ? 0.0f : table[bucket];
        atomicAdd(&acc[wave][f], e * v);                 // ds_add_f32
    }
    __syncthreads();

    if (tid < NUM_SEGMENTS) {
        float sum = 0.0f;
        #pragma unroll
        for (int w = 0; w < NWAVES; ++w) sum += acc[w][tid];
        if (tid >= 1) out[(long)b * NUM_FIELDS + (tid - 1)] = sum;  // drop field 0
    }
}

extern "C" void kernel_launch(void* const* d_in, const int* in_sizes, int n_in,
                              void* d_out, int out_size, void* d_ws, size_t ws_size,
                              hipStream_t stream) {
    const int*   indexes = (const int*)  d_in[0];
    const int*   fields  = (const int*)  d_in[1];
    const float* values  = (const float*)d_in[2];
    const float* table   = (const float*)d_in[3];
    float*       out     = (float*)      d_out;

    wide_pool_kernel<<<BATCH, BLOCK, 0, stream>>>(indexes, fields, values, table, out);
}